// Round 3
// baseline (543.377 us; speedup 1.0000x reference)
//
#include <hip/hip_runtime.h>
#include <math.h>

#define Bn 64
#define Hn 1024
#define BH 65536          // Bn * Hn

// native vector type for nontemporal builtins (HIP_vector_type not accepted)
typedef float v4f __attribute__((ext_vector_type(4)));

// ws layout (floats):
//   [0      ,  6*BH) : final gate region; only slot 3 (k_t) used, written by C
//   [6*BH   ,      ) : raw GEMM partials, 144 slots of BH:
//        slots [0,32)  : i   (32 K-tiles of 64)
//        slots [32,64) : f
//        slots [64,96) : o
//        slots [96,112): k   (16 K-tiles)
//        slots [112,128): v
//        slots [128,144): q
//   [WS_NP  ,      ) : ngate (m = k_t @ We) partials, 16 K-splits
#define WS_GP (6 * BH)
#define NSLOT 144
#define SLOT_I 0
#define SLOT_F 32
#define SLOT_O 64
#define SLOT_K 96
#define SLOT_V 112
#define SLOT_Q 128
#define WS_NP (WS_GP + NSLOT * BH)

// ---------------------------------------------------------------------------
// Kernel A: one 64x64x64 GEMM tile per block (no bias, no activation).
//   grid = (16 n-tiles, 144 (gate,k-tile) pairs) = 2304 uniform blocks.
//   ys < 96  : g = ys>>5 (i,f,o),  s = ys&31, K-tile s of 32 (K=2048)
//   ys >= 96 : g = 3 + (ys-96)>>4, s = (ys-96)&15, K-tile s of 16 (K=1024)
//   Thread = 4 consecutive cols (float4 weight loads) x 4 rows.
// ---------------------------------------------------------------------------
__global__ __launch_bounds__(256) void gates_partial(
    const float* __restrict__ x, const float* __restrict__ h_prev,
    const float* __restrict__ Wi, const float* __restrict__ Wf,
    const float* __restrict__ Wo, const float* __restrict__ Wk,
    const float* __restrict__ Wv, const float* __restrict__ Wq,
    float* __restrict__ ws)
{
    const int ys = blockIdx.y;
    int g, s;
    if (ys < 96) { g = ys >> 5; s = ys & 31; }
    else         { const int t2 = ys - 96; g = 3 + (t2 >> 4); s = t2 & 15; }

    const float* Wm;
    switch (g) {
        case 0: Wm = Wi; break; case 1: Wm = Wf; break;
        case 2: Wm = Wo; break; case 3: Wm = Wk; break;
        case 4: Wm = Wv; break; default: Wm = Wq; break;
    }
    const int k0 = s << 6;
    const float* Ab;
    int kloc;
    if (g < 3)       { Ab = (k0 < 1024) ? x : h_prev; kloc = k0 & 1023; }
    else if (g == 5) { Ab = h_prev; kloc = k0; }
    else             { Ab = x;      kloc = k0; }

    __shared__ float A_lds[64][68];   // +4 pad

    const int t  = threadIdx.x;
    const int cg = t & 15;            // col group: 4 consecutive cols
    const int rg = t >> 4;            // 0..15
    const int n0 = (blockIdx.x << 6) + (cg << 2);

    {   // cooperative stage: 64 rows x 64 k-cols
        const int c = cg << 2;
        #pragma unroll
        for (int rr = 0; rr < 4; ++rr) {
            const int row = rg + (rr << 4);
            *(float4*)&A_lds[row][c] =
                *(const float4*)&Ab[(size_t)row * 1024 + kloc + c];
        }
    }
    __syncthreads();

    float4 acc[4];
    #pragma unroll
    for (int r = 0; r < 4; ++r) acc[r] = make_float4(0.f, 0.f, 0.f, 0.f);

    #pragma unroll 2
    for (int kk = 0; kk < 64; kk += 4) {
        const float* wp = Wm + (size_t)(k0 + kk) * 1024 + n0;
        const float4 w0 = *(const float4*)(wp);
        const float4 w1 = *(const float4*)(wp + 1024);
        const float4 w2 = *(const float4*)(wp + 2048);
        const float4 w3 = *(const float4*)(wp + 3072);
        #pragma unroll
        for (int r = 0; r < 4; ++r) {
            const float4 a = *(const float4*)&A_lds[(rg << 2) + r][kk];
            acc[r].x += a.x * w0.x + a.y * w1.x + a.z * w2.x + a.w * w3.x;
            acc[r].y += a.x * w0.y + a.y * w1.y + a.z * w2.y + a.w * w3.y;
            acc[r].z += a.x * w0.z + a.y * w1.z + a.z * w2.z + a.w * w3.z;
            acc[r].w += a.x * w0.w + a.y * w1.w + a.z * w2.w + a.w * w3.w;
        }
    }

    float* P = ws + WS_GP + (size_t)ys * BH;
    #pragma unroll
    for (int r = 0; r < 4; ++r)
        *(float4*)&P[(size_t)((rg << 2) + r) * 1024 + n0] = acc[r];
}

// ---------------------------------------------------------------------------
// Kernel C: m = k_t @ We partials. Depends ONLY on kernel A: builds its k_t
// tile by summing the 16 raw k-partials (+bk) during staging. nx==0 blocks
// also store the finalized k_t tile for kernel E. grid (16, 16).
// ---------------------------------------------------------------------------
__global__ __launch_bounds__(256) void ngate_partial(
    const float* __restrict__ We, const float* __restrict__ bk,
    float* __restrict__ ws)
{
    const int s  = blockIdx.y;           // 0..15 (k-tile of k_t)
    const int nx = blockIdx.x;
    const int k0 = s << 6;

    __shared__ float A_lds[64][68];

    const int t  = threadIdx.x;
    const int cg = t & 15;
    const int rg = t >> 4;
    const int n0 = (nx << 6) + (cg << 2);
    const int c  = cg << 2;

    {   // build k_t tile: sum 16 k-partials + bias
        const float4 kb = *(const float4*)&bk[k0 + c];
        #pragma unroll
        for (int rr = 0; rr < 4; ++rr) {
            const int row = rg + (rr << 4);
            float4 a = kb;
            #pragma unroll
            for (int ss = 0; ss < 16; ++ss) {
                const float4 p = *(const float4*)&ws[WS_GP
                    + (size_t)(SLOT_K + ss) * BH + (size_t)row * 1024 + k0 + c];
                a.x += p.x; a.y += p.y; a.z += p.z; a.w += p.w;
            }
            *(float4*)&A_lds[row][c] = a;
            if (nx == 0)   // store finalized k_t for kernel E (disjoint per s)
                *(float4*)&ws[(size_t)3 * BH + (size_t)row * 1024 + k0 + c] = a;
        }
    }
    __syncthreads();

    float4 acc[4];
    #pragma unroll
    for (int r = 0; r < 4; ++r) acc[r] = make_float4(0.f, 0.f, 0.f, 0.f);

    #pragma unroll 2
    for (int kk = 0; kk < 64; kk += 4) {
        const float* wp = We + (size_t)(k0 + kk) * 1024 + n0;
        const float4 w0 = *(const float4*)(wp);
        const float4 w1 = *(const float4*)(wp + 1024);
        const float4 w2 = *(const float4*)(wp + 2048);
        const float4 w3 = *(const float4*)(wp + 3072);
        #pragma unroll
        for (int r = 0; r < 4; ++r) {
            const float4 a = *(const float4*)&A_lds[(rg << 2) + r][kk];
            acc[r].x += a.x * w0.x + a.y * w1.x + a.z * w2.x + a.w * w3.x;
            acc[r].y += a.x * w0.y + a.y * w1.y + a.z * w2.y + a.w * w3.y;
            acc[r].z += a.x * w0.z + a.y * w1.z + a.z * w2.z + a.w * w3.z;
            acc[r].w += a.x * w0.w + a.y * w1.w + a.z * w2.w + a.w * w3.w;
        }
    }

    float* P = ws + WS_NP + (size_t)s * BH;
    #pragma unroll
    for (int r = 0; r < 4; ++r)
        *(float4*)&P[(size_t)((rg << 2) + r) * 1024 + n0] = acc[r];
}

// ---------------------------------------------------------------------------
// Kernel E: full finalize + C update + h_t. 64 rows/block, grid 1024 blocks
// (XCD-swizzled so the 16 blocks of a batch row share q/k in one L2).
//   Phase 1a (all 256 thr): q_t = sum 16 q-partials + bq  -> LDS
//   Phase 1b (thr 0..63)  : per-row scalars — i,f,o (32 partials each),
//                           v (16), m (16); sigmoid/exp; n_t; f, i*v, o/n ->LDS
//   Phase 2 (16 rows/wave): C_t = f*C_prev + (i*v)*k_t ; h_t = (o/n)*(C_t.q)
// ---------------------------------------------------------------------------
__global__ __launch_bounds__(256) void c_update(
    const float* __restrict__ C_prev, const float* __restrict__ ws,
    const float* __restrict__ bi, const float* __restrict__ bf,
    const float* __restrict__ bo, const float* __restrict__ bv,
    const float* __restrict__ bq, const float* __restrict__ be,
    const float* __restrict__ n_prev,
    float* __restrict__ h_t, float* __restrict__ C_t,
    float* __restrict__ n_out)
{
    __shared__ float q_f[1024];
    __shared__ float fs[64], ivs[64], on[64];

    const int t    = threadIdx.x;
    const int orig = blockIdx.x;
    const int swz  = ((orig & 7) << 7) + (orig >> 3);   // bijective, 1024 % 8 == 0
    const int R0   = swz << 6;                          // first of 64 rows
    const int b    = R0 >> 10;

    {   // phase 1a: finalize q for this batch row (float4 per thread)
        float4 a = *(const float4*)&bq[t << 2];
        const float* base = ws + WS_GP + (size_t)SLOT_Q * BH
                          + (size_t)b * 1024 + (t << 2);
        #pragma unroll
        for (int ss = 0; ss < 16; ++ss) {
            const float4 p = *(const float4*)(base + (size_t)ss * BH);
            a.x += p.x; a.y += p.y; a.z += p.z; a.w += p.w;
        }
        *(float4*)&q_f[t << 2] = a;
    }

    if (t < 64) {   // phase 1b: per-row scalar finalize (coalesced across thr)
        const int R = R0 + t;
        const int n = R & 1023;
        float iv = bi[n], fv = bf[n], ov = bo[n], vv = bv[n], mv = be[n];
        const float* G = ws + WS_GP;
        #pragma unroll 4
        for (int ss = 0; ss < 32; ++ss) iv += G[(size_t)(SLOT_I + ss) * BH + R];
        #pragma unroll 4
        for (int ss = 0; ss < 32; ++ss) fv += G[(size_t)(SLOT_F + ss) * BH + R];
        #pragma unroll 4
        for (int ss = 0; ss < 32; ++ss) ov += G[(size_t)(SLOT_O + ss) * BH + R];
        #pragma unroll 4
        for (int ss = 0; ss < 16; ++ss) vv += G[(size_t)(SLOT_V + ss) * BH + R];
        #pragma unroll 4
        for (int ss = 0; ss < 16; ++ss) mv += ws[WS_NP + (size_t)ss * BH + R];
        const float ig = 1.f / (1.f + expf(-iv));
        const float fg = 1.f / (1.f + expf(-fv));
        const float og = 1.f / (1.f + expf(-ov));
        const float nt = fg * n_prev[R] + ig * expf(mv);
        n_out[R] = nt;
        fs[t]  = fg;
        ivs[t] = ig * vv;
        on[t]  = og / nt;
    }
    __syncthreads();

    // phase 2: stream C. 4 waves x 16 rows.
    const int lane = t & 63;
    const int w    = t >> 6;

    float4 k4[4], q4[4];
    const float4* kp = (const float4*)(ws + 3 * BH + (size_t)b * 1024);
    #pragma unroll
    for (int c = 0; c < 4; ++c) {
        k4[c] = kp[c * 64 + lane];
        q4[c] = *(const float4*)&q_f[(c * 64 + lane) << 2];
    }

    #pragma unroll 2
    for (int r = 0; r < 16; ++r) {
        const int lr = (w << 4) + r;        // local row 0..63
        const int R  = R0 + lr;
        const float f  = fs[lr];
        const float iv = ivs[lr];

        const v4f* cp = (const v4f*)(C_prev + (size_t)R * 1024);
        v4f*       co = (v4f*)(C_t + (size_t)R * 1024);

        float dot = 0.f;
        #pragma unroll
        for (int c = 0; c < 4; ++c) {
            const v4f c4 = __builtin_nontemporal_load(&cp[c * 64 + lane]);
            v4f o4;
            o4.x = f * c4.x + iv * k4[c].x;
            o4.y = f * c4.y + iv * k4[c].y;
            o4.z = f * c4.z + iv * k4[c].z;
            o4.w = f * c4.w + iv * k4[c].w;
            __builtin_nontemporal_store(o4, &co[c * 64 + lane]);
            dot += o4.x * q4[c].x + o4.y * q4[c].y
                 + o4.z * q4[c].z + o4.w * q4[c].w;
        }
        #pragma unroll
        for (int off = 32; off; off >>= 1)
            dot += __shfl_xor(dot, off);
        if (lane == 0)
            h_t[R] = on[lr] * dot;
    }
}

// ---------------------------------------------------------------------------
extern "C" void kernel_launch(void* const* d_in, const int* in_sizes, int n_in,
                              void* d_out, int out_size, void* d_ws, size_t ws_size,
                              hipStream_t stream)
{
    const float* x      = (const float*)d_in[0];
    const float* h_prev = (const float*)d_in[1];
    const float* C_prev = (const float*)d_in[2];
    const float* n_prev = (const float*)d_in[3];
    const float* Wi = (const float*)d_in[4];  const float* bi = (const float*)d_in[5];
    const float* Wf = (const float*)d_in[6];  const float* bf = (const float*)d_in[7];
    const float* Wo = (const float*)d_in[8];  const float* bo = (const float*)d_in[9];
    const float* Wk = (const float*)d_in[10]; const float* bk = (const float*)d_in[11];
    const float* Wv = (const float*)d_in[12]; const float* bv = (const float*)d_in[13];
    const float* Wq = (const float*)d_in[14]; const float* bq = (const float*)d_in[15];
    const float* We = (const float*)d_in[16]; const float* be = (const float*)d_in[17];

    float* out = (float*)d_out;
    float* h_t = out;                                 // [B,H]
    float* C_t = out + BH;                            // [B,H,H]
    float* n_t = out + BH + (size_t)Bn * Hn * Hn;     // [B,H]
    float* ws  = (float*)d_ws;

    gates_partial<<<dim3(16, 144), 256, 0, stream>>>(
        x, h_prev, Wi, Wf, Wo, Wk, Wv, Wq, ws);

    ngate_partial<<<dim3(16, 16), 256, 0, stream>>>(We, bk, ws);

    c_update<<<1024, 256, 0, stream>>>(
        C_prev, ws, bi, bf, bo, bv, bq, be, n_prev, h_t, C_t, n_t);
}